// Round 1
// baseline (281.597 us; speedup 1.0000x reference)
//
#include <hip/hip_runtime.h>

#define OH 224
#define OW 224
#define HH 1024
#define WW 1024
#define CC 3

__global__ __launch_bounds__(256) void adaptive_sam_kernel(
    const float* __restrict__ x,
    const float* __restrict__ sh,
    const float* __restrict__ sw,
    const float* __restrict__ wgt,
    float* __restrict__ out,
    int B)
{
    __shared__ float ws[81];
    if (threadIdx.x < 81) ws[threadIdx.x] = wgt[threadIdx.x];
    __syncthreads();

    int site = blockIdx.x * blockDim.x + threadIdx.x;
    const int total = B * OH * OW;
    if (site >= total) return;

    int j = site % OW;
    int t = site / OW;
    int i = t % OH;
    int b = t / OH;

    float ch = (sh[b * OH + i] + 1.0f) * ((HH - 1) * 0.5f);
    float cw = (sw[b * OW + j] + 1.0f) * ((WW - 1) * 0.5f);
    float cyf = floorf(ch); float fy = ch - cyf; int iy = (int)cyf;
    float cxf = floorf(cw); float fx = cw - cxf; int ix = (int)cxf;

    // Clipped patch coordinates (4 rows, 4 cols) and per-tap masked weights.
    int rrow[4], ccol[4];
    #pragma unroll
    for (int a = 0; a < 4; ++a) {
        int r = iy - 1 + a;
        rrow[a] = min(max(r, 0), HH - 1);
        int c = ix - 1 + a;
        ccol[a] = min(max(c, 0), WW - 1);
    }
    float wy0[3], wy1[3], wx0[3], wx1[3];
    #pragma unroll
    for (int u = 0; u < 3; ++u) {
        int y0 = iy + u - 1, y1 = y0 + 1;
        wy0[u] = (1.0f - fy) * ((y0 >= 0 && y0 < HH) ? 1.0f : 0.0f);
        wy1[u] = fy          * ((y1 >= 0 && y1 < HH) ? 1.0f : 0.0f);
        int x0 = ix + u - 1, x1 = x0 + 1;
        wx0[u] = (1.0f - fx) * ((x0 >= 0 && x0 < WW) ? 1.0f : 0.0f);
        wx1[u] = fx          * ((x1 >= 0 && x1 < WW) ? 1.0f : 0.0f);
    }

    float acc0 = 0.0f, acc1 = 0.0f, acc2 = 0.0f;
    #pragma unroll
    for (int c = 0; c < CC; ++c) {
        const float* xc = x + (size_t)(b * CC + c) * (HH * WW);
        float P[4][4];
        #pragma unroll
        for (int a = 0; a < 4; ++a) {
            const float* row = xc + (size_t)rrow[a] * WW;
            #pragma unroll
            for (int bb = 0; bb < 4; ++bb)
                P[a][bb] = row[ccol[bb]];
        }
        // horizontal lerp: 4 rows x 3 v-taps
        float hx[4][3];
        #pragma unroll
        for (int a = 0; a < 4; ++a)
            #pragma unroll
            for (int v = 0; v < 3; ++v)
                hx[a][v] = wx0[v] * P[a][v] + wx1[v] * P[a][v + 1];
        // vertical lerp + contraction with weight
        #pragma unroll
        for (int u = 0; u < 3; ++u)
            #pragma unroll
            for (int v = 0; v < 3; ++v) {
                float s = wy0[u] * hx[u][v] + wy1[u] * hx[u + 1][v];
                int wi = c * 9 + u * 3 + v;
                acc0 = fmaf(ws[0 * 27 + wi], s, acc0);
                acc1 = fmaf(ws[1 * 27 + wi], s, acc1);
                acc2 = fmaf(ws[2 * 27 + wi], s, acc2);
            }
    }

    size_t obase = (size_t)b * CC * OH * OW + (size_t)i * OW + j;
    out[obase]               = acc0;
    out[obase + OH * OW]     = acc1;
    out[obase + 2 * OH * OW] = acc2;
}

extern "C" void kernel_launch(void* const* d_in, const int* in_sizes, int n_in,
                              void* d_out, int out_size, void* d_ws, size_t ws_size,
                              hipStream_t stream) {
    const float* x  = (const float*)d_in[0];
    const float* sh = (const float*)d_in[1];
    const float* sw = (const float*)d_in[2];
    const float* w  = (const float*)d_in[3];
    float* out = (float*)d_out;

    int B = in_sizes[1] / OH;           // stride_h is [B, 224]
    int total = B * OH * OW;
    dim3 grid((total + 255) / 256);
    adaptive_sam_kernel<<<grid, 256, 0, stream>>>(x, sh, sw, w, out, B);
}

// Round 3
// 266.517 us; speedup vs baseline: 1.0566x; 1.0566x over previous
//
#include <hip/hip_runtime.h>

#define OH 224
#define OW 224
#define HH 1024
#define WW 1024

// 16B vector load with only 4B alignment guarantee (gfx950 supports
// unaligned global dwordx4; avoids UB of casting to float4 which is align-16).
typedef float f4u __attribute__((ext_vector_type(4), aligned(4)));

__global__ __launch_bounds__(256) void adaptive_sam_kernel(
    const float* __restrict__ x,
    const float* __restrict__ sh,
    const float* __restrict__ sw,
    const float* __restrict__ wgt,
    float* __restrict__ out,
    int B)
{
    __shared__ float ws[81];
    if (threadIdx.x < 81) ws[threadIdx.x] = wgt[threadIdx.x];
    __syncthreads();

    int site = blockIdx.x * blockDim.x + threadIdx.x;
    const int total = B * OH * OW;
    if (site >= total) return;

    int j = site % OW;
    int t = site / OW;
    int i = t % OH;
    int b = t / OH;

    float chf = (sh[b * OH + i] + 1.0f) * ((HH - 1) * 0.5f);
    float cwf = (sw[b * OW + j] + 1.0f) * ((WW - 1) * 0.5f);
    float cyf = floorf(chf); float fy = chf - cyf; int iy = (int)cyf;
    float cxf = floorf(cwf); float fx = cwf - cxf; int ix = (int)cxf;

    // Physical 4x4 patch origin (clamped so patch stays in-bounds).
    int rb = min(max(iy - 1, 0), HH - 4);
    int cb = min(max(ix - 1, 0), WW - 4);

    // Wy[u][p]: weight of physical row rb+p for vertical tap u (clip folded in).
    // Wx[v][p]: weight of physical col cb+p for horizontal tap v.
    float Wy[3][4], Wx[3][4];
    #pragma unroll
    for (int u = 0; u < 3; ++u) {
        int y0 = iy + u - 1, y1 = y0 + 1;
        float a0 = (1.0f - fy) * ((y0 >= 0 && y0 < HH) ? 1.0f : 0.0f);
        float a1 = fy          * ((y1 >= 0 && y1 < HH) ? 1.0f : 0.0f);
        int py0 = min(max(y0, 0), HH - 1) - rb;
        int py1 = min(max(y1, 0), HH - 1) - rb;

        int x0 = ix + u - 1, x1 = x0 + 1;
        float b0 = (1.0f - fx) * ((x0 >= 0 && x0 < WW) ? 1.0f : 0.0f);
        float b1 = fx          * ((x1 >= 0 && x1 < WW) ? 1.0f : 0.0f);
        int px0 = min(max(x0, 0), WW - 1) - cb;
        int px1 = min(max(x1, 0), WW - 1) - cb;

        #pragma unroll
        for (int p = 0; p < 4; ++p) {
            Wy[u][p] = (py0 == p ? a0 : 0.0f) + (py1 == p ? a1 : 0.0f);
            Wx[u][p] = (px0 == p ? b0 : 0.0f) + (px1 == p ? b1 : 0.0f);
        }
    }

    float acc0 = 0.0f, acc1 = 0.0f, acc2 = 0.0f;
    const float* xb = x + (size_t)b * 3 * HH * WW;

    #pragma unroll
    for (int c = 0; c < 3; ++c) {
        const float* pr = xb + (size_t)c * HH * WW + (size_t)rb * WW + cb;
        f4u q0 = *reinterpret_cast<const f4u*>(pr);
        f4u q1 = *reinterpret_cast<const f4u*>(pr + WW);
        f4u q2 = *reinterpret_cast<const f4u*>(pr + 2 * WW);
        f4u q3 = *reinterpret_cast<const f4u*>(pr + 3 * WW);

        // horizontal pass: hx[p][v] = sum_k Wx[v][k] * q_p[k]
        float hx[4][3];
        #pragma unroll
        for (int v = 0; v < 3; ++v) {
            hx[0][v] = Wx[v][0]*q0.x + Wx[v][1]*q0.y + Wx[v][2]*q0.z + Wx[v][3]*q0.w;
            hx[1][v] = Wx[v][0]*q1.x + Wx[v][1]*q1.y + Wx[v][2]*q1.z + Wx[v][3]*q1.w;
            hx[2][v] = Wx[v][0]*q2.x + Wx[v][1]*q2.y + Wx[v][2]*q2.z + Wx[v][3]*q2.w;
            hx[3][v] = Wx[v][0]*q3.x + Wx[v][1]*q3.y + Wx[v][2]*q3.z + Wx[v][3]*q3.w;
        }
        // vertical pass + weight contraction
        #pragma unroll
        for (int u = 0; u < 3; ++u)
            #pragma unroll
            for (int v = 0; v < 3; ++v) {
                float s = Wy[u][0]*hx[0][v] + Wy[u][1]*hx[1][v]
                        + Wy[u][2]*hx[2][v] + Wy[u][3]*hx[3][v];
                int wi = c * 9 + u * 3 + v;
                acc0 = fmaf(ws[wi],      s, acc0);
                acc1 = fmaf(ws[27 + wi], s, acc1);
                acc2 = fmaf(ws[54 + wi], s, acc2);
            }
    }

    size_t obase = (size_t)b * 3 * OH * OW + (size_t)i * OW + j;
    out[obase]               = acc0;
    out[obase + OH * OW]     = acc1;
    out[obase + 2 * OH * OW] = acc2;
}

extern "C" void kernel_launch(void* const* d_in, const int* in_sizes, int n_in,
                              void* d_out, int out_size, void* d_ws, size_t ws_size,
                              hipStream_t stream) {
    const float* x  = (const float*)d_in[0];
    const float* sh = (const float*)d_in[1];
    const float* sw = (const float*)d_in[2];
    const float* w  = (const float*)d_in[3];
    float* out = (float*)d_out;

    int B = in_sizes[1] / OH;           // stride_h is [B, 224]
    int total = B * OH * OW;
    dim3 grid((total + 255) / 256);
    adaptive_sam_kernel<<<grid, 256, 0, stream>>>(x, sh, sw, w, out, B);
}

// Round 5
// 262.759 us; speedup vs baseline: 1.0717x; 1.0143x over previous
//
#include <hip/hip_runtime.h>

#define OH 224
#define OW 224
#define HH 1024
#define WW 1024
#define HW (HH * WW)

typedef __attribute__((address_space(3))) void lds_void_t;
typedef const __attribute__((address_space(1))) void g_void_t;

__global__ __launch_bounds__(256) void adaptive_sam_kernel(
    const float* __restrict__ x,
    const float* __restrict__ sh,
    const float* __restrict__ sw,
    const float* __restrict__ wgt,
    float* __restrict__ out,
    int B)
{
    // Linear LDS (required by global_load_lds: dest = uniform base + lane*16).
    __shared__ float lds[3 * 4 * WW];   // 48 KB: [c][r][w]
    __shared__ float ws[81];

    const int tid = threadIdx.x;
    const int bi  = blockIdx.x;         // = b*OH + i
    const int i   = bi % OH;
    const int b   = bi / OH;

    if (tid < 81) ws[tid] = wgt[tid];

    // Block-uniform vertical coordinate.
    float chf = (sh[b * OH + i] + 1.0f) * ((HH - 1) * 0.5f);
    float cyf = floorf(chf); float fy = chf - cyf; int iy = (int)cyf;
    int rb = min(max(iy - 1, 0), HH - 4);   // physical 4-row window, in-bounds

    // Stage x[b, c, rb..rb+3, :] (3 x 16 KB contiguous) into LDS.
    // 4 waves; wave wv stages 4 KB (4 x 1KB chunks) of each channel.
    {
        const int lane = tid & 63;
        const int wv   = tid >> 6;
        #pragma unroll
        for (int c = 0; c < 3; ++c) {
            const float* gbase = x + (size_t)(b * 3 + c) * HW + (size_t)rb * WW + wv * 1024;
            float* lbase = &lds[c * 4096 + wv * 1024];
            #pragma unroll
            for (int n = 0; n < 4; ++n) {
                const float* gp = gbase + n * 256 + lane * 4;   // 16B per lane
                __builtin_amdgcn_global_load_lds((g_void_t*)gp,
                                                 (lds_void_t*)(lbase + n * 256),
                                                 16, 0, 0);
            }
        }
    }
    __syncthreads();   // compiler drains vmcnt before s_barrier

    if (tid < OW) {
        const int j = tid;
        float cwf = (sw[b * OW + j] + 1.0f) * ((WW - 1) * 0.5f);
        float cxf = floorf(cwf); float fx = cwf - cxf; int ix = (int)cxf;
        int cb = min(max(ix - 1, 0), WW - 4);

        // Fold clipping/duplication into per-axis 3x4 weight matrices.
        float Wy[3][4], Wx[3][4];
        #pragma unroll
        for (int u = 0; u < 3; ++u) {
            int y0 = iy + u - 1, y1 = y0 + 1;
            float a0 = (1.0f - fy) * ((y0 >= 0 && y0 < HH) ? 1.0f : 0.0f);
            float a1 = fy          * ((y1 >= 0 && y1 < HH) ? 1.0f : 0.0f);
            int py0 = min(max(y0, 0), HH - 1) - rb;
            int py1 = min(max(y1, 0), HH - 1) - rb;

            int x0 = ix + u - 1, x1 = x0 + 1;
            float b0 = (1.0f - fx) * ((x0 >= 0 && x0 < WW) ? 1.0f : 0.0f);
            float b1 = fx          * ((x1 >= 0 && x1 < WW) ? 1.0f : 0.0f);
            int px0 = min(max(x0, 0), WW - 1) - cb;
            int px1 = min(max(x1, 0), WW - 1) - cb;

            #pragma unroll
            for (int p = 0; p < 4; ++p) {
                Wy[u][p] = (py0 == p ? a0 : 0.0f) + (py1 == p ? a1 : 0.0f);
                Wx[u][p] = (px0 == p ? b0 : 0.0f) + (px1 == p ? b1 : 0.0f);
            }
        }

        float acc0 = 0.0f, acc1 = 0.0f, acc2 = 0.0f;
        #pragma unroll
        for (int c = 0; c < 3; ++c) {
            float hx[4][3];
            #pragma unroll
            for (int r = 0; r < 4; ++r) {
                const float* lp = &lds[c * 4096 + r * 1024 + cb];
                float p0 = lp[0], p1 = lp[1], p2 = lp[2], p3 = lp[3];
                #pragma unroll
                for (int v = 0; v < 3; ++v)
                    hx[r][v] = Wx[v][0] * p0 + Wx[v][1] * p1
                             + Wx[v][2] * p2 + Wx[v][3] * p3;
            }
            #pragma unroll
            for (int u = 0; u < 3; ++u)
                #pragma unroll
                for (int v = 0; v < 3; ++v) {
                    float s = Wy[u][0] * hx[0][v] + Wy[u][1] * hx[1][v]
                            + Wy[u][2] * hx[2][v] + Wy[u][3] * hx[3][v];
                    int wi = c * 9 + u * 3 + v;
                    acc0 = fmaf(ws[wi],      s, acc0);
                    acc1 = fmaf(ws[27 + wi], s, acc1);
                    acc2 = fmaf(ws[54 + wi], s, acc2);
                }
        }

        size_t obase = (size_t)b * 3 * OH * OW + (size_t)i * OW + j;
        out[obase]                = acc0;
        out[obase + OH * OW]      = acc1;
        out[obase + 2 * OH * OW]  = acc2;
    }
}

extern "C" void kernel_launch(void* const* d_in, const int* in_sizes, int n_in,
                              void* d_out, int out_size, void* d_ws, size_t ws_size,
                              hipStream_t stream) {
    const float* x  = (const float*)d_in[0];
    const float* sh = (const float*)d_in[1];
    const float* sw = (const float*)d_in[2];
    const float* w  = (const float*)d_in[3];
    float* out = (float*)d_out;

    int B = in_sizes[1] / OH;           // stride_h is [B, 224]
    dim3 grid(B * OH);                  // one block per (b, i) output row
    adaptive_sam_kernel<<<grid, 256, 0, stream>>>(x, sh, sw, w, out, B);
}